// Round 12
// baseline (189.411 us; speedup 1.0000x reference)
//
#include <hip/hip_runtime.h>

#define EPSV 1e-5f

typedef __attribute__((ext_vector_type(8))) short short8v;
typedef __attribute__((ext_vector_type(4))) float f32x4;

static __device__ __forceinline__ unsigned short f2bf(float f) {
  unsigned int u = __float_as_uint(f);
  u += 0x7fff + ((u >> 16) & 1);
  return (unsigned short)(u >> 16);
}
static __device__ __forceinline__ float bf2f(unsigned short h) {
  return __uint_as_float(((unsigned int)h) << 16);
}

// async global->LDS 16B: dest = wave-uniform base + lane*16 (linear)
static __device__ __forceinline__ void glds16(const void* g, void* l) {
  __builtin_amdgcn_global_load_lds(
      (const __attribute__((address_space(1))) void*)g,
      (__attribute__((address_space(3))) void*)l, 16, 0, 0);
}

// ---------------------------------------------------------------------------
// Fused prep: blocks [0,1280) NCHW->NHWC bf16; [1280,3584) conv-w reorder
// (+zpad zero); [3584,4864) GAT weight transposes.
// ---------------------------------------------------------------------------
__global__ __launch_bounds__(256) void prep_fused_kernel(
    const float* __restrict__ x, unsigned short* __restrict__ xin,
    const float* __restrict__ cw, unsigned short* __restrict__ Wr,
    float* __restrict__ zpad,
    const float* __restrict__ wq, const float* __restrict__ wk,
    const float* __restrict__ wv, const float* __restrict__ wo,
    const float* __restrict__ rec, float* __restrict__ wT)
{
  __shared__ unsigned short t[80 * 257];
  const int bid = blockIdx.x;
  if (bid < 1280) {
    int b = bid / 80, y = bid - b * 80;
    const float* src = x + (size_t)b * 256 * 6400 + y * 80;
    for (int e = threadIdx.x; e < 256 * 20; e += 256) {
      int c = e / 20;
      int px4 = e - c * 20;
      f32x4 v = *(const f32x4*)&src[(size_t)c * 6400 + px4 * 4];
#pragma unroll
      for (int j = 0; j < 4; ++j)
        t[(px4 * 4 + j) * 257 + c] = f2bf(v[j]);
    }
    __syncthreads();
    unsigned short* dst = xin + (size_t)bid * 80 * 256;
    for (int e = threadIdx.x; e < 80 * 32; e += 256) {
      int px = e >> 5;
      int c8 = e & 31;
      short8v v;
#pragma unroll
      for (int j = 0; j < 8; ++j) v[j] = t[px * 257 + c8 * 8 + j];
      *(short8v*)&dst[px * 256 + c8 * 8] = v;
    }
  } else if (bid < 3584) {
    if (bid == 1280) zpad[threadIdx.x] = 0.f;
    int idx = (bid - 1280) * 256 + threadIdx.x;
    int cil = idx & 31;
    int rest = idx >> 5;
    int co = rest & 255;
    int tcc = rest >> 8;
    int cc = tcc & 7;
    int tt = tcc >> 3;
    int dy = tt / 3, dx = tt - dy * 3;
    int ci = cc * 32 + cil;
    Wr[idx] = f2bf(cw[((co * 256 + ci) * 3 + dy) * 3 + dx]);
  } else {
    int idx = (bid - 3584) * 256 + threadIdx.x;
    int m = idx >> 16;
    int e = idx & 65535;
    int ci = e >> 8, co = e & 255;
    const float* src = (m == 0) ? wq : (m == 1) ? wk : (m == 2) ? wv
                     : (m == 3) ? wo : rec;
    wT[idx] = src[co * 256 + ci];
  }
}

// ---------------------------------------------------------------------------
// Fused direct conv@roi-pixels + BN + SiLU + bilinear avg -> nodes[512][256].
// Block per NODE PAIR (R9-verified): 512 thr / 8 waves = 2(node) x 4(co64).
// W staged once per step, shared by both nodes. 3-deep buffer rotation
// (buf = t%3), counted s_waitcnt vmcnt(3) + raw s_barrier.
// ---------------------------------------------------------------------------
__global__ __launch_bounds__(512, 1) void roiconv_kernel(
    const unsigned short* __restrict__ xin,   // zpad zeros at byte 52428800
    const float* __restrict__ boxes,
    const float* __restrict__ convb,
    const float* __restrict__ bn1g, const float* __restrict__ bn1b,
    const float* __restrict__ bn1m, const float* __restrict__ bn1v,
    const unsigned short* __restrict__ Wr,
    float* __restrict__ nodes)
{
  const int bid = blockIdx.x;
  const int pr = (bid & 7) * 32 + (bid >> 3);  // XCD-bijective (256%8==0)
  const int tid = threadIdx.x;
  const int nd = tid >> 8;                      // this thread's node (0/1)
  const int n = pr * 2 + nd;
  const int b = n >> 5;
  const int w = tid >> 6, lane = tid & 63;
  const int bq = lane >> 4, r16 = lane & 15;
  const int wr = w >> 2, wc = w & 3;            // wave: node, co-64 group

  // IN bufs: 3 x 8192 @ 0/8192/16384; W bufs: 3 x 16384 @ 24576/40960/57344;
  // wcoef[128] @ 73728. Epilogue bf16 ep[128][264] = 67584B reuses 0..67583.
  __shared__ __align__(16) char lds[74240];
  float* wcoef = (float*)(lds + 73728);
  const int INB = 0, WB = 24576;

  // ---- geometry for this thread's corner pixel pc = (tid>>2)&63 ----
  const int pc = (tid >> 2) & 63;
  const float* bx = boxes + n * 4;
  float x1 = bx[0] * 79.f, y1 = bx[1] * 79.f, x2 = bx[2] * 79.f, y2 = bx[3] * 79.f;
  float rwd = fmaxf(x2 - x1, 1.f), rh = fmaxf(y2 - y1, 1.f);
  int s = pc >> 2;
  int sy = s >> 2, sx = s & 3;
  float yy = y1 + (sy + 0.5f) * 0.25f * rh;
  float xx = x1 + (sx + 0.5f) * 0.25f * rwd;
  bool valid = (yy >= -1.f) && (yy <= 80.f) && (xx >= -1.f) && (xx <= 80.f);
  float yc = fminf(fmaxf(yy, 0.f), 79.f), xc = fminf(fmaxf(xx, 0.f), 79.f);
  float y0f = floorf(yc), x0f = floorf(xc);
  int y0i = (int)y0f, x0i = (int)x0f;
  int y1i = min(y0i + 1, 79), x1i = min(x0i + 1, 79);
  float ly = yc - y0f, lx = xc - x0f, hy = 1.f - ly, hx = 1.f - lx;
  int py = (pc & 2) ? y1i : y0i;
  int pxx = (pc & 1) ? x1i : x0i;
  if ((tid & 3) == 0)
    wcoef[tid >> 2] = ((pc & 2) ? ly : hy) * ((pc & 1) ? lx : hx) *
                      (valid ? 0.0625f : 0.f);

  // ---- staging source offsets (bits 1-2 of pc drive both sides) ----
  const int chunk = (tid & 3) ^ ((pc >> 1) & 3);
  unsigned ioff[9];
#pragma unroll
  for (int t = 0; t < 9; ++t) {
    int dy = t / 3, dx = t - dy * 3;
    int cy = py + dy - 1, cx = pxx + dx - 1;
    bool ok = ((unsigned)cy < 80u) && ((unsigned)cx < 80u);
    ioff[t] = ok ? (unsigned)((((b * 80 + cy) * 80 + cx) * 256 + chunk * 8) * 2)
                 : 52428800u;
  }
  unsigned woff[2];
#pragma unroll
  for (int i = 0; i < 2; ++i) {
    int s2 = tid + (i << 9);
    int wco = s2 >> 2;
    int wch = (s2 & 3) ^ ((wco >> 1) & 3);
    woff[i] = (unsigned)((wco * 32 + wch * 8) * 2);
  }
  const int laneoff = r16 * 64 + ((bq ^ ((r16 >> 1) & 3)) << 4);
  const char* xinb = (const char*)xin;
  const char* Wrb = (const char*)Wr;
  const int ldwave = w << 10;                   // w*1024: wave-uniform dest

  f32x4 acc[4][4];
#pragma unroll
  for (int i = 0; i < 4; ++i)
#pragma unroll
    for (int j = 0; j < 4; ++j)
      acc[i][j] = (f32x4){0.f, 0.f, 0.f, 0.f};

  // prologue: issue steps 0 (buf0) and 1 (buf1); 3 issues/thread/step
  glds16(xinb + ioff[0], lds + INB + ldwave);
  glds16(Wrb + woff[0], lds + WB + ldwave);
  glds16(Wrb + woff[1], lds + WB + 8192 + ldwave);
  glds16(xinb + ioff[1], lds + INB + 8192 + ldwave);
  glds16(Wrb + ((size_t)8 << 14) + woff[0], lds + WB + 16384 + ldwave);
  glds16(Wrb + ((size_t)8 << 14) + woff[1], lds + WB + 16384 + 8192 + ldwave);

  for (int cc = 0; cc < 8; ++cc) {
#pragma unroll
    for (int t = 0; t < 9; ++t) {
      const int cb = t % 3;                     // compile-time buffer index
      const char* inb = lds + INB + cb * 8192;
      const char* wb  = lds + WB + cb * 16384;
      // counted wait: keep step+1's 3 loads in flight; tail drains fully
      if (cc == 7 && t == 8)
        asm volatile("s_waitcnt vmcnt(0)" ::: "memory");
      else
        asm volatile("s_waitcnt vmcnt(3)" ::: "memory");
      __builtin_amdgcn_s_barrier();
      __builtin_amdgcn_sched_barrier(0);
      // issue step+2 (buffer (t+2)%3, last read at step-1 -> barrier-ordered)
      if (!(cc == 7 && t >= 7)) {
        const int nt = (t + 2 > 8) ? t - 7 : t + 2;   // compile-time
        const int nb = nt % 3;
        const int ncc = cc + (t >= 7 ? 1 : 0);
        char* innx = lds + INB + nb * 8192;
        char* wbn  = lds + WB + nb * 16384;
        glds16(xinb + ioff[nt] + ncc * 64, innx + ldwave);
        const char* wg = Wrb + ((size_t)(nt * 8 + ncc) << 14);
        glds16(wg + woff[0], wbn + ldwave);
        glds16(wg + woff[1], wbn + 8192 + ldwave);
      }
      const char* pa = inb + wr * 4096 + laneoff;
      const char* pw = wb + wc * 4096 + laneoff;
      short8v af0 = *(const short8v*)(pa);
      short8v af1 = *(const short8v*)(pa + 1024);
      short8v af2 = *(const short8v*)(pa + 2048);
      short8v af3 = *(const short8v*)(pa + 3072);
      short8v wf0 = *(const short8v*)(pw);
      short8v wf1 = *(const short8v*)(pw + 1024);
      short8v wf2 = *(const short8v*)(pw + 2048);
      short8v wf3 = *(const short8v*)(pw + 3072);
      __builtin_amdgcn_s_setprio(1);
      acc[0][0] = __builtin_amdgcn_mfma_f32_16x16x32_bf16(af0, wf0, acc[0][0], 0, 0, 0);
      acc[0][1] = __builtin_amdgcn_mfma_f32_16x16x32_bf16(af0, wf1, acc[0][1], 0, 0, 0);
      acc[0][2] = __builtin_amdgcn_mfma_f32_16x16x32_bf16(af0, wf2, acc[0][2], 0, 0, 0);
      acc[0][3] = __builtin_amdgcn_mfma_f32_16x16x32_bf16(af0, wf3, acc[0][3], 0, 0, 0);
      acc[1][0] = __builtin_amdgcn_mfma_f32_16x16x32_bf16(af1, wf0, acc[1][0], 0, 0, 0);
      acc[1][1] = __builtin_amdgcn_mfma_f32_16x16x32_bf16(af1, wf1, acc[1][1], 0, 0, 0);
      acc[1][2] = __builtin_amdgcn_mfma_f32_16x16x32_bf16(af1, wf2, acc[1][2], 0, 0, 0);
      acc[1][3] = __builtin_amdgcn_mfma_f32_16x16x32_bf16(af1, wf3, acc[1][3], 0, 0, 0);
      acc[2][0] = __builtin_amdgcn_mfma_f32_16x16x32_bf16(af2, wf0, acc[2][0], 0, 0, 0);
      acc[2][1] = __builtin_amdgcn_mfma_f32_16x16x32_bf16(af2, wf1, acc[2][1], 0, 0, 0);
      acc[2][2] = __builtin_amdgcn_mfma_f32_16x16x32_bf16(af2, wf2, acc[2][2], 0, 0, 0);
      acc[2][3] = __builtin_amdgcn_mfma_f32_16x16x32_bf16(af2, wf3, acc[2][3], 0, 0, 0);
      acc[3][0] = __builtin_amdgcn_mfma_f32_16x16x32_bf16(af3, wf0, acc[3][0], 0, 0, 0);
      acc[3][1] = __builtin_amdgcn_mfma_f32_16x16x32_bf16(af3, wf1, acc[3][1], 0, 0, 0);
      acc[3][2] = __builtin_amdgcn_mfma_f32_16x16x32_bf16(af3, wf2, acc[3][2], 0, 0, 0);
      acc[3][3] = __builtin_amdgcn_mfma_f32_16x16x32_bf16(af3, wf3, acc[3][3], 0, 0, 0);
      __builtin_amdgcn_s_setprio(0);
    }
  }
  __syncthreads();

  // epilogue: bias+BN+SiLU -> bf16 ep[128][264]; then bilinear combine (f32)
  unsigned short* ep = (unsigned short*)lds;
#pragma unroll
  for (int cf = 0; cf < 4; ++cf) {
    int co = wc * 64 + cf * 16 + r16;
    float sc = bn1g[co] / sqrtf(bn1v[co] + EPSV);
    float sh = bn1b[co] - bn1m[co] * sc;
    float cb = convb[co];
#pragma unroll
    for (int mf = 0; mf < 4; ++mf) {
#pragma unroll
      for (int rg = 0; rg < 4; ++rg) {
        int pxo = wr * 64 + mf * 16 + bq * 4 + rg;  // D row (m89)
        float v = (acc[mf][cf][rg] + cb) * sc + sh;
        v = v / (1.f + __expf(-v));                 // SiLU
        ep[pxo * 264 + co] = f2bf(v);
      }
    }
  }
  __syncthreads();
  const int c = tid & 255;
  float val = 0.f;
#pragma unroll
  for (int p = 0; p < 64; ++p)
    val += wcoef[nd * 64 + p] * bf2f(ep[(nd * 64 + p) * 264 + c]);
  nodes[n * 256 + c] = val;
}

// ---------------------------------------------------------------------------
// q,k,v projections. Block = (node-quad, co-half): grid 256. Thread handles
// 2 nodes x 1 co. Same wT traffic as 4-node blocks, 2x CU coverage.
// ---------------------------------------------------------------------------
__global__ __launch_bounds__(256) void qkv_kernel(
    const float* __restrict__ nodes, const float* __restrict__ wT,
    const float* __restrict__ bq, const float* __restrict__ bk,
    const float* __restrict__ bv,
    float* __restrict__ q, float* __restrict__ k, float* __restrict__ v)
{
  const int blk = blockIdx.x;
  const int nq = blk >> 1, coh = blk & 1;
  const int t = threadIdx.x;
  const int co = coh * 128 + (t & 127);
  const int half = t >> 7;                  // nodes half*2 .. half*2+1
  __shared__ float nd[4][256];
  for (int i = t; i < 1024; i += 256)
    nd[i >> 8][i & 255] = nodes[nq * 1024 + i];
  __syncthreads();
  float aq[2] = {0, 0}, ak[2] = {0, 0}, av[2] = {0, 0};
  const float* wqT = wT;
  const float* wkT = wT + 65536;
  const float* wvT = wT + 131072;
  for (int ci = 0; ci < 256; ++ci) {
    float wq_ = wqT[ci * 256 + co];
    float wk_ = wkT[ci * 256 + co];
    float wv_ = wvT[ci * 256 + co];
#pragma unroll
    for (int r = 0; r < 2; ++r) {
      float nv = nd[half * 2 + r][ci];
      aq[r] += nv * wq_;
      ak[r] += nv * wk_;
      av[r] += nv * wv_;
    }
  }
  float bq_ = bq[co], bk_ = bk[co], bv_ = bv[co];
#pragma unroll
  for (int r = 0; r < 2; ++r) {
    int n = nq * 4 + half * 2 + r;
    q[n * 256 + co] = aq[r] + bq_;
    k[n * 256 + co] = ak[r] + bk_;
    v[n * 256 + co] = av[r] + bv_;
  }
}

// ---------------------------------------------------------------------------
// Multi-head attention core: block per (head, 16-query chunk) = 256 blocks.
// K_h, V_h staged in LDS [512][32] f32 with chunk-XOR swizzle (~2-way free).
// Scores in regs (32/thread), softmax via 16-wide shfl, P bf16 in LDS,
// PV per (query, d-pair) -> msgs[512][256].
// ---------------------------------------------------------------------------
__global__ __launch_bounds__(256) void attn_mh_kernel(
    const float* __restrict__ q, const float* __restrict__ k,
    const float* __restrict__ v, const float* __restrict__ scale_p,
    float* __restrict__ msgs)
{
  const int bid = blockIdx.x;
  const int h = bid & 7, qc = bid >> 3;       // qc 0..31
  const int q0 = qc * 16;
  const int tid = threadIdx.x;
  __shared__ __align__(16) float Kh[512 * 32];
  __shared__ __align__(16) float Vh[512 * 32];
  __shared__ unsigned short pb[16 * 512];

  for (int idx = tid; idx < 4096; idx += 256) {
    int j = idx >> 3, part = idx & 7;
    int chs = part ^ (j & 7);
    *(f32x4*)&Kh[j * 32 + chs * 4] =
        *(const f32x4*)&k[(size_t)j * 256 + h * 32 + part * 4];
    *(f32x4*)&Vh[j * 32 + chs * 4] =
        *(const f32x4*)&v[(size_t)j * 256 + h * 32 + part * 4];
  }
  const int qi = tid >> 4, l = tid & 15;
  f32x4 qr[8];
#pragma unroll
  for (int p = 0; p < 8; ++p)
    qr[p] = *(const f32x4*)&q[(size_t)(q0 + qi) * 256 + h * 32 + p * 4];
  const float scale = scale_p[0];
  __syncthreads();

  float pj[32];
  float mx = -1e30f;
#pragma unroll
  for (int jj = 0; jj < 32; ++jj) {
    int j = jj * 16 + l;
    const float* kr = &Kh[j * 32];
    int sw = j & 7;
    float s = 0.f;
#pragma unroll
    for (int p = 0; p < 8; ++p) {
      f32x4 kv = *(const f32x4*)&kr[(p ^ sw) * 4];
      s += kv.x * qr[p].x + kv.y * qr[p].y + kv.z * qr[p].z + kv.w * qr[p].w;
    }
    s *= scale;
    pj[jj] = s;
    mx = fmaxf(mx, s);
  }
#pragma unroll
  for (int o = 1; o < 16; o <<= 1) mx = fmaxf(mx, __shfl_xor(mx, o, 16));
  float sum = 0.f;
#pragma unroll
  for (int jj = 0; jj < 32; ++jj) {
    float e = __expf(pj[jj] - mx);
    pj[jj] = e;
    sum += e;
  }
#pragma unroll
  for (int o = 1; o < 16; o <<= 1) sum += __shfl_xor(sum, o, 16);
  float inv = 1.f / sum;
#pragma unroll
  for (int jj = 0; jj < 32; ++jj)
    pb[qi * 512 + jj * 16 + l] = f2bf(pj[jj] * inv);
  __syncthreads();

  // PV: thread (qi, d-pair l): d0 = 2l
  float m0 = 0.f, m1 = 0.f;
  const unsigned short* pq = &pb[qi * 512];
  for (int j = 0; j < 512; ++j) {
    float p = bf2f(pq[j]);
    int chs = (l >> 1) ^ (j & 7);
    const float* vr = &Vh[j * 32 + chs * 4 + ((2 * l) & 3)];
    m0 += p * vr[0];
    m1 += p * vr[1];
  }
  float* mo = &msgs[(size_t)(q0 + qi) * 256 + h * 32 + 2 * l];
  mo[0] = m0;
  mo[1] = m1;
}

// ---------------------------------------------------------------------------
// Out-proj + residual + LayerNorm. Block per 8 nodes (amortizes wo reads).
// ---------------------------------------------------------------------------
__global__ __launch_bounds__(256) void outln_kernel(
    const float* __restrict__ msgs, const float* __restrict__ nodes,
    const float* __restrict__ woT, const float* __restrict__ bo,
    const float* __restrict__ lng, const float* __restrict__ lnb,
    float* __restrict__ enh)
{
  const int blk = blockIdx.x;
  const int co = threadIdx.x;
  __shared__ float ms[8][256];
  __shared__ float red1[8][4], red2[8][4];
  for (int i = co; i < 2048; i += 256)
    ms[i >> 8][i & 255] = msgs[blk * 2048 + i];
  __syncthreads();
  float yv[8];
  float bo_ = bo[co];
#pragma unroll
  for (int r = 0; r < 8; ++r)
    yv[r] = nodes[(size_t)(blk * 8 + r) * 256 + co] + bo_;
  for (int ci = 0; ci < 256; ++ci) {
    float w = woT[ci * 256 + co];
#pragma unroll
    for (int r = 0; r < 8; ++r) yv[r] += ms[r][ci] * w;
  }
  const int wv = co >> 6, lane = co & 63;
#pragma unroll
  for (int r = 0; r < 8; ++r) {
    float s1 = yv[r], s2 = yv[r] * yv[r];
#pragma unroll
    for (int o = 1; o < 64; o <<= 1) {
      s1 += __shfl_xor(s1, o);
      s2 += __shfl_xor(s2, o);
    }
    if (lane == 0) { red1[r][wv] = s1; red2[r][wv] = s2; }
  }
  __syncthreads();
  float lg = lng[co], lb = lnb[co];
#pragma unroll
  for (int r = 0; r < 8; ++r) {
    float S1 = red1[r][0] + red1[r][1] + red1[r][2] + red1[r][3];
    float S2 = red2[r][0] + red2[r][1] + red2[r][2] + red2[r][3];
    float mu = S1 * (1.f / 256.f);
    float var = S2 * (1.f / 256.f) - mu * mu;
    enh[(size_t)(blk * 8 + r) * 256 + co] =
        (yv[r] - mu) * rsqrtf(var + EPSV) * lg + lb;
  }
}

// ---------------------------------------------------------------------------
// Per-batch pooling + rec 1x1 conv + BN2 -> yfin[b][c]. Block per batch.
// ---------------------------------------------------------------------------
__global__ __launch_bounds__(256) void final_kernel(
    const float* __restrict__ enh, const float* __restrict__ recT,
    const float* __restrict__ recb,
    const float* __restrict__ bn2g, const float* __restrict__ bn2b,
    const float* __restrict__ bn2m, const float* __restrict__ bn2v,
    float* __restrict__ yfin)
{
  const int b = blockIdx.x;
  const int tid = threadIdx.x;
  const int wv = tid >> 6, l = tid & 63;
  __shared__ float rm[32], wts[32], wgt[256];
  for (int kk = wv; kk < 32; kk += 4) {
    const float* er = enh + (size_t)(b * 32 + kk) * 256;
    float s = er[l] + er[l + 64] + er[l + 128] + er[l + 192];
#pragma unroll
    for (int o = 1; o < 64; o <<= 1) s += __shfl_xor(s, o);
    if (l == 0) rm[kk] = s * (1.f / 256.f);
  }
  __syncthreads();
  if (tid < 32) {
    float m = rm[tid];
    float mx = m;
#pragma unroll
    for (int o = 1; o < 32; o <<= 1) mx = fmaxf(mx, __shfl_xor(mx, o, 32));
    float e = __expf(m - mx);
    float sm = e;
#pragma unroll
    for (int o = 1; o < 32; o <<= 1) sm += __shfl_xor(sm, o, 32);
    wts[tid] = e / sm;
  }
  __syncthreads();
  float wsum = 0.f;
  for (int kk = 0; kk < 32; ++kk)
    wsum += enh[(size_t)(b * 32 + kk) * 256 + tid] * wts[kk];
  wgt[tid] = wsum;
  __syncthreads();
  const int co = tid;
  float yv = recb[co];
  for (int ci = 0; ci < 256; ++ci)
    yv += wgt[ci] * recT[ci * 256 + co];
  float s = bn2g[co] / sqrtf(bn2v[co] + EPSV);
  yfin[b * 256 + co] = yv * s + (bn2b[co] - bn2m[co] * s);
}

// ---------------------------------------------------------------------------
// out = x + yfin broadcast, reading xin (NHWC bf16, 52MB) instead of x
// (100MB). Block per (b,y): coalesced row read -> LDS [80][258] -> f32x4
// NCHW writes ordered (c, px4): 320B runs, 4 runs/wave.
// ---------------------------------------------------------------------------
__global__ __launch_bounds__(256) void add_kernel(
    const unsigned short* __restrict__ xin, const float* __restrict__ yfin,
    float* __restrict__ out)
{
  const int bid = blockIdx.x;
  const int b = bid / 80, y = bid - b * 80;
  const int tid = threadIdx.x;
  __shared__ unsigned short ep[80 * 258];
  __shared__ float yf[256];
  const unsigned short* src = xin + (size_t)bid * 80 * 256;
  for (int idx = tid; idx < 2560; idx += 256) {
    int px = idx >> 5;
    int c8 = idx & 31;
    *(short8v*)&ep[px * 258 + c8 * 8] = *(const short8v*)&src[px * 256 + c8 * 8];
  }
  yf[tid] = yfin[b * 256 + tid];
  __syncthreads();
  float* ob = out + (size_t)b * 256 * 6400 + y * 80;
#pragma unroll
  for (int k2 = 0; k2 < 20; ++k2) {
    int idx = k2 * 256 + tid;                 // (c, px4): c = idx/20
    int c = idx / 20;
    int px4 = idx - c * 20;
    float a = yf[c];
    f32x4 v;
#pragma unroll
    for (int j = 0; j < 4; ++j)
      v[j] = bf2f(ep[(px4 * 4 + j) * 258 + c]) + a;
    *(f32x4*)&ob[(size_t)c * 6400 + px4 * 4] = v;
  }
}

extern "C" void kernel_launch(void* const* d_in, const int* in_sizes, int n_in,
                              void* d_out, int out_size, void* d_ws, size_t ws_size,
                              hipStream_t stream)
{
  const float* x      = (const float*)d_in[0];
  const float* boxes  = (const float*)d_in[1];
  const float* conv_w = (const float*)d_in[2];
  const float* conv_b = (const float*)d_in[3];
  const float* bn1g   = (const float*)d_in[4];
  const float* bn1b   = (const float*)d_in[5];
  const float* bn1m   = (const float*)d_in[6];
  const float* bn1v   = (const float*)d_in[7];
  const float* wq     = (const float*)d_in[8];
  const float* bq     = (const float*)d_in[9];
  const float* wk     = (const float*)d_in[10];
  const float* bkp    = (const float*)d_in[11];
  const float* wv     = (const float*)d_in[12];
  const float* bv     = (const float*)d_in[13];
  const float* scale  = (const float*)d_in[14];
  const float* wo     = (const float*)d_in[15];
  const float* bo     = (const float*)d_in[16];
  const float* lng    = (const float*)d_in[17];
  const float* lnb    = (const float*)d_in[18];
  const float* rec_w  = (const float*)d_in[19];
  const float* rec_b  = (const float*)d_in[20];
  const float* bn2g   = (const float*)d_in[21];
  const float* bn2b   = (const float*)d_in[22];
  const float* bn2m   = (const float*)d_in[23];
  const float* bn2v   = (const float*)d_in[24];
  float* out = (float*)d_out;

  char* ws = (char*)d_ws;
  unsigned short* Wr = (unsigned short*)(ws);                // 1,179,648 B
  float* wT    = (float*)(ws + 2097152);                     // 1,310,720 B
  float* nodes = (float*)(ws + 4194304);
  float* qb    = nodes + 131072;
  float* kb    = qb + 131072;
  float* vb    = kb + 131072;
  float* enh   = vb + 131072;
  float* yfin  = enh + 131072;                               // 16 KB
  float* msgs  = yfin + 4096;                                // 512 KB
  // xin (NHWC bf16, 52.4 MB) + 1KB zero pad in d_ws. zpad directly follows
  // xin so roiconv's OOB offset (52428800) lands in it. Re-zeroed every call.
  unsigned short* xin = (unsigned short*)(ws + 8388608);
  float* zpad = (float*)(ws + 8388608 + 52428800);

  hipLaunchKernelGGL(prep_fused_kernel, dim3(4864), dim3(256), 0, stream,
                     x, xin, conv_w, Wr, zpad, wq, wk, wv, wo, rec_w, wT);
  hipLaunchKernelGGL(roiconv_kernel, dim3(256), dim3(512), 0, stream,
                     xin, boxes, conv_b, bn1g, bn1b, bn1m, bn1v, Wr, nodes);
  hipLaunchKernelGGL(qkv_kernel, dim3(256), dim3(256), 0, stream,
                     nodes, wT, bq, bkp, bv, qb, kb, vb);
  hipLaunchKernelGGL(attn_mh_kernel, dim3(256), dim3(256), 0, stream,
                     qb, kb, vb, scale, msgs);
  hipLaunchKernelGGL(outln_kernel, dim3(64), dim3(256), 0, stream,
                     msgs, nodes, wT + 3 * 65536, bo, lng, lnb, enh);
  hipLaunchKernelGGL(final_kernel, dim3(16), dim3(256), 0, stream,
                     enh, wT + 4 * 65536, rec_b, bn2g, bn2b, bn2m, bn2v, yfin);
  hipLaunchKernelGGL(add_kernel, dim3(1280), dim3(256), 0, stream,
                     xin, yfin, out);
}

// Round 13
// 183.032 us; speedup vs baseline: 1.0349x; 1.0349x over previous
//
#include <hip/hip_runtime.h>

#define EPSV 1e-5f

typedef __attribute__((ext_vector_type(8))) short short8v;
typedef __attribute__((ext_vector_type(4))) float f32x4;

static __device__ __forceinline__ unsigned short f2bf(float f) {
  unsigned int u = __float_as_uint(f);
  u += 0x7fff + ((u >> 16) & 1);
  return (unsigned short)(u >> 16);
}
static __device__ __forceinline__ float bf2f(unsigned short h) {
  return __uint_as_float(((unsigned int)h) << 16);
}

// async global->LDS 16B: dest = wave-uniform base + lane*16 (linear)
static __device__ __forceinline__ void glds16(const void* g, void* l) {
  __builtin_amdgcn_global_load_lds(
      (const __attribute__((address_space(1))) void*)g,
      (__attribute__((address_space(3))) void*)l, 16, 0, 0);
}

// ---------------------------------------------------------------------------
// Fused prep: blocks [0,1280) NCHW->NHWC bf16; [1280,3584) conv-w reorder
// (+zpad zero); [3584,4864) GAT weight transposes.
// ---------------------------------------------------------------------------
__global__ __launch_bounds__(256) void prep_fused_kernel(
    const float* __restrict__ x, unsigned short* __restrict__ xin,
    const float* __restrict__ cw, unsigned short* __restrict__ Wr,
    float* __restrict__ zpad,
    const float* __restrict__ wq, const float* __restrict__ wk,
    const float* __restrict__ wv, const float* __restrict__ wo,
    const float* __restrict__ rec, float* __restrict__ wT)
{
  __shared__ unsigned short t[80 * 257];
  const int bid = blockIdx.x;
  if (bid < 1280) {
    int b = bid / 80, y = bid - b * 80;
    const float* src = x + (size_t)b * 256 * 6400 + y * 80;
    for (int e = threadIdx.x; e < 256 * 20; e += 256) {
      int c = e / 20;
      int px4 = e - c * 20;
      f32x4 v = *(const f32x4*)&src[(size_t)c * 6400 + px4 * 4];
#pragma unroll
      for (int j = 0; j < 4; ++j)
        t[(px4 * 4 + j) * 257 + c] = f2bf(v[j]);
    }
    __syncthreads();
    unsigned short* dst = xin + (size_t)bid * 80 * 256;
    for (int e = threadIdx.x; e < 80 * 32; e += 256) {
      int px = e >> 5;
      int c8 = e & 31;
      short8v v;
#pragma unroll
      for (int j = 0; j < 8; ++j) v[j] = t[px * 257 + c8 * 8 + j];
      *(short8v*)&dst[px * 256 + c8 * 8] = v;
    }
  } else if (bid < 3584) {
    if (bid == 1280) zpad[threadIdx.x] = 0.f;
    int idx = (bid - 1280) * 256 + threadIdx.x;
    int cil = idx & 31;
    int rest = idx >> 5;
    int co = rest & 255;
    int tcc = rest >> 8;
    int cc = tcc & 7;
    int tt = tcc >> 3;
    int dy = tt / 3, dx = tt - dy * 3;
    int ci = cc * 32 + cil;
    Wr[idx] = f2bf(cw[((co * 256 + ci) * 3 + dy) * 3 + dx]);
  } else {
    int idx = (bid - 3584) * 256 + threadIdx.x;
    int m = idx >> 16;
    int e = idx & 65535;
    int ci = e >> 8, co = e & 255;
    const float* src = (m == 0) ? wq : (m == 1) ? wk : (m == 2) ? wv
                     : (m == 3) ? wo : rec;
    wT[idx] = src[co * 256 + ci];
  }
}

// ---------------------------------------------------------------------------
// Fused direct conv@roi-pixels + BN + SiLU + bilinear avg -> nodes[512][256].
// Block per NODE PAIR (R9-verified best): 512 thr / 8 waves = 2(node) x
// 4(co64). W staged once per step, shared by both nodes. 3-deep buffer
// rotation (buf = t%3), counted s_waitcnt vmcnt(3) + raw s_barrier.
// ---------------------------------------------------------------------------
__global__ __launch_bounds__(512, 1) void roiconv_kernel(
    const unsigned short* __restrict__ xin,   // zpad zeros at byte 52428800
    const float* __restrict__ boxes,
    const float* __restrict__ convb,
    const float* __restrict__ bn1g, const float* __restrict__ bn1b,
    const float* __restrict__ bn1m, const float* __restrict__ bn1v,
    const unsigned short* __restrict__ Wr,
    float* __restrict__ nodes)
{
  const int bid = blockIdx.x;
  const int pr = (bid & 7) * 32 + (bid >> 3);  // XCD-bijective (256%8==0)
  const int tid = threadIdx.x;
  const int nd = tid >> 8;                      // this thread's node (0/1)
  const int n = pr * 2 + nd;
  const int b = n >> 5;
  const int w = tid >> 6, lane = tid & 63;
  const int bq = lane >> 4, r16 = lane & 15;
  const int wr = w >> 2, wc = w & 3;            // wave: node, co-64 group

  // IN bufs: 3 x 8192 @ 0/8192/16384; W bufs: 3 x 16384 @ 24576/40960/57344;
  // wcoef[128] @ 73728. Epilogue bf16 ep[128][264] = 67584B reuses 0..67583.
  __shared__ __align__(16) char lds[74240];
  float* wcoef = (float*)(lds + 73728);
  const int INB = 0, WB = 24576;

  // ---- geometry for this thread's corner pixel pc = (tid>>2)&63 ----
  const int pc = (tid >> 2) & 63;
  const float* bx = boxes + n * 4;
  float x1 = bx[0] * 79.f, y1 = bx[1] * 79.f, x2 = bx[2] * 79.f, y2 = bx[3] * 79.f;
  float rwd = fmaxf(x2 - x1, 1.f), rh = fmaxf(y2 - y1, 1.f);
  int s = pc >> 2;
  int sy = s >> 2, sx = s & 3;
  float yy = y1 + (sy + 0.5f) * 0.25f * rh;
  float xx = x1 + (sx + 0.5f) * 0.25f * rwd;
  bool valid = (yy >= -1.f) && (yy <= 80.f) && (xx >= -1.f) && (xx <= 80.f);
  float yc = fminf(fmaxf(yy, 0.f), 79.f), xc = fminf(fmaxf(xx, 0.f), 79.f);
  float y0f = floorf(yc), x0f = floorf(xc);
  int y0i = (int)y0f, x0i = (int)x0f;
  int y1i = min(y0i + 1, 79), x1i = min(x0i + 1, 79);
  float ly = yc - y0f, lx = xc - x0f, hy = 1.f - ly, hx = 1.f - lx;
  int py = (pc & 2) ? y1i : y0i;
  int pxx = (pc & 1) ? x1i : x0i;
  if ((tid & 3) == 0)
    wcoef[tid >> 2] = ((pc & 2) ? ly : hy) * ((pc & 1) ? lx : hx) *
                      (valid ? 0.0625f : 0.f);

  // ---- staging source offsets (bits 1-2 of pc drive both sides) ----
  const int chunk = (tid & 3) ^ ((pc >> 1) & 3);
  unsigned ioff[9];
#pragma unroll
  for (int t = 0; t < 9; ++t) {
    int dy = t / 3, dx = t - dy * 3;
    int cy = py + dy - 1, cx = pxx + dx - 1;
    bool ok = ((unsigned)cy < 80u) && ((unsigned)cx < 80u);
    ioff[t] = ok ? (unsigned)((((b * 80 + cy) * 80 + cx) * 256 + chunk * 8) * 2)
                 : 52428800u;
  }
  unsigned woff[2];
#pragma unroll
  for (int i = 0; i < 2; ++i) {
    int s2 = tid + (i << 9);
    int wco = s2 >> 2;
    int wch = (s2 & 3) ^ ((wco >> 1) & 3);
    woff[i] = (unsigned)((wco * 32 + wch * 8) * 2);
  }
  const int laneoff = r16 * 64 + ((bq ^ ((r16 >> 1) & 3)) << 4);
  const char* xinb = (const char*)xin;
  const char* Wrb = (const char*)Wr;
  const int ldwave = w << 10;                   // w*1024: wave-uniform dest

  f32x4 acc[4][4];
#pragma unroll
  for (int i = 0; i < 4; ++i)
#pragma unroll
    for (int j = 0; j < 4; ++j)
      acc[i][j] = (f32x4){0.f, 0.f, 0.f, 0.f};

  // prologue: issue steps 0 (buf0) and 1 (buf1); 3 issues/thread/step
  glds16(xinb + ioff[0], lds + INB + ldwave);
  glds16(Wrb + woff[0], lds + WB + ldwave);
  glds16(Wrb + woff[1], lds + WB + 8192 + ldwave);
  glds16(xinb + ioff[1], lds + INB + 8192 + ldwave);
  glds16(Wrb + ((size_t)8 << 14) + woff[0], lds + WB + 16384 + ldwave);
  glds16(Wrb + ((size_t)8 << 14) + woff[1], lds + WB + 16384 + 8192 + ldwave);

  for (int cc = 0; cc < 8; ++cc) {
#pragma unroll
    for (int t = 0; t < 9; ++t) {
      const int cb = t % 3;                     // compile-time buffer index
      const char* inb = lds + INB + cb * 8192;
      const char* wb  = lds + WB + cb * 16384;
      // counted wait: keep step+1's 3 loads in flight; tail drains fully
      if (cc == 7 && t == 8)
        asm volatile("s_waitcnt vmcnt(0)" ::: "memory");
      else
        asm volatile("s_waitcnt vmcnt(3)" ::: "memory");
      __builtin_amdgcn_s_barrier();
      __builtin_amdgcn_sched_barrier(0);
      // issue step+2 (buffer (t+2)%3, last read at step-1 -> barrier-ordered)
      if (!(cc == 7 && t >= 7)) {
        const int nt = (t + 2 > 8) ? t - 7 : t + 2;   // compile-time
        const int nb = nt % 3;
        const int ncc = cc + (t >= 7 ? 1 : 0);
        char* innx = lds + INB + nb * 8192;
        char* wbn  = lds + WB + nb * 16384;
        glds16(xinb + ioff[nt] + ncc * 64, innx + ldwave);
        const char* wg = Wrb + ((size_t)(nt * 8 + ncc) << 14);
        glds16(wg + woff[0], wbn + ldwave);
        glds16(wg + woff[1], wbn + 8192 + ldwave);
      }
      const char* pa = inb + wr * 4096 + laneoff;
      const char* pw = wb + wc * 4096 + laneoff;
      short8v af0 = *(const short8v*)(pa);
      short8v af1 = *(const short8v*)(pa + 1024);
      short8v af2 = *(const short8v*)(pa + 2048);
      short8v af3 = *(const short8v*)(pa + 3072);
      short8v wf0 = *(const short8v*)(pw);
      short8v wf1 = *(const short8v*)(pw + 1024);
      short8v wf2 = *(const short8v*)(pw + 2048);
      short8v wf3 = *(const short8v*)(pw + 3072);
      __builtin_amdgcn_s_setprio(1);
      acc[0][0] = __builtin_amdgcn_mfma_f32_16x16x32_bf16(af0, wf0, acc[0][0], 0, 0, 0);
      acc[0][1] = __builtin_amdgcn_mfma_f32_16x16x32_bf16(af0, wf1, acc[0][1], 0, 0, 0);
      acc[0][2] = __builtin_amdgcn_mfma_f32_16x16x32_bf16(af0, wf2, acc[0][2], 0, 0, 0);
      acc[0][3] = __builtin_amdgcn_mfma_f32_16x16x32_bf16(af0, wf3, acc[0][3], 0, 0, 0);
      acc[1][0] = __builtin_amdgcn_mfma_f32_16x16x32_bf16(af1, wf0, acc[1][0], 0, 0, 0);
      acc[1][1] = __builtin_amdgcn_mfma_f32_16x16x32_bf16(af1, wf1, acc[1][1], 0, 0, 0);
      acc[1][2] = __builtin_amdgcn_mfma_f32_16x16x32_bf16(af1, wf2, acc[1][2], 0, 0, 0);
      acc[1][3] = __builtin_amdgcn_mfma_f32_16x16x32_bf16(af1, wf3, acc[1][3], 0, 0, 0);
      acc[2][0] = __builtin_amdgcn_mfma_f32_16x16x32_bf16(af2, wf0, acc[2][0], 0, 0, 0);
      acc[2][1] = __builtin_amdgcn_mfma_f32_16x16x32_bf16(af2, wf1, acc[2][1], 0, 0, 0);
      acc[2][2] = __builtin_amdgcn_mfma_f32_16x16x32_bf16(af2, wf2, acc[2][2], 0, 0, 0);
      acc[2][3] = __builtin_amdgcn_mfma_f32_16x16x32_bf16(af2, wf3, acc[2][3], 0, 0, 0);
      acc[3][0] = __builtin_amdgcn_mfma_f32_16x16x32_bf16(af3, wf0, acc[3][0], 0, 0, 0);
      acc[3][1] = __builtin_amdgcn_mfma_f32_16x16x32_bf16(af3, wf1, acc[3][1], 0, 0, 0);
      acc[3][2] = __builtin_amdgcn_mfma_f32_16x16x32_bf16(af3, wf2, acc[3][2], 0, 0, 0);
      acc[3][3] = __builtin_amdgcn_mfma_f32_16x16x32_bf16(af3, wf3, acc[3][3], 0, 0, 0);
      __builtin_amdgcn_s_setprio(0);
    }
  }
  __syncthreads();

  // epilogue: bias+BN+SiLU -> bf16 ep[128][264]; then bilinear combine (f32)
  unsigned short* ep = (unsigned short*)lds;
#pragma unroll
  for (int cf = 0; cf < 4; ++cf) {
    int co = wc * 64 + cf * 16 + r16;
    float sc = bn1g[co] / sqrtf(bn1v[co] + EPSV);
    float sh = bn1b[co] - bn1m[co] * sc;
    float cb = convb[co];
#pragma unroll
    for (int mf = 0; mf < 4; ++mf) {
#pragma unroll
      for (int rg = 0; rg < 4; ++rg) {
        int pxo = wr * 64 + mf * 16 + bq * 4 + rg;  // D row (m89)
        float v = (acc[mf][cf][rg] + cb) * sc + sh;
        v = v / (1.f + __expf(-v));                 // SiLU
        ep[pxo * 264 + co] = f2bf(v);
      }
    }
  }
  __syncthreads();
  const int c = tid & 255;
  float val = 0.f;
#pragma unroll
  for (int p = 0; p < 64; ++p)
    val += wcoef[nd * 64 + p] * bf2f(ep[(nd * 64 + p) * 264 + c]);
  nodes[n * 256 + c] = val;
}

// ---------------------------------------------------------------------------
// q,k,v projections. Block handles 4 nodes (grid 128); thread = out channel.
// ---------------------------------------------------------------------------
__global__ __launch_bounds__(256) void qkv_kernel(
    const float* __restrict__ nodes, const float* __restrict__ wT,
    const float* __restrict__ bq, const float* __restrict__ bk,
    const float* __restrict__ bv,
    float* __restrict__ q, float* __restrict__ k, float* __restrict__ v)
{
  const int blk = blockIdx.x;
  const int co = threadIdx.x;
  __shared__ float nd[4][256];
  for (int i = threadIdx.x; i < 1024; i += 256)
    nd[i >> 8][i & 255] = nodes[blk * 1024 + i];
  __syncthreads();
  float aq[4] = {0, 0, 0, 0};
  float ak[4] = {0, 0, 0, 0};
  float av[4] = {0, 0, 0, 0};
  const float* wqT = wT;
  const float* wkT = wT + 65536;
  const float* wvT = wT + 131072;
  for (int ci = 0; ci < 256; ++ci) {
    float wq_ = wqT[ci * 256 + co];
    float wk_ = wkT[ci * 256 + co];
    float wv_ = wvT[ci * 256 + co];
#pragma unroll
    for (int r = 0; r < 4; ++r) {
      float nv = nd[r][ci];
      aq[r] += nv * wq_;
      ak[r] += nv * wk_;
      av[r] += nv * wv_;
    }
  }
  float bq_ = bq[co], bk_ = bk[co], bv_ = bv[co];
#pragma unroll
  for (int r = 0; r < 4; ++r) {
    int n = blk * 4 + r;
    q[n * 256 + co] = aq[r] + bq_;
    k[n * 256 + co] = ak[r] + bk_;
    v[n * 256 + co] = av[r] + bv_;
  }
}

// ---------------------------------------------------------------------------
// Multi-head attention core: block per (head, 16-query chunk) = 256 blocks.
// K_h, V_h staged in LDS [512][32] f32 with chunk-XOR swizzle (~2-way free).
// Scores in regs (32/thread), softmax via 16-wide shfl, P bf16 in LDS,
// PV per (query, d-pair) -> msgs[512][256].
// ---------------------------------------------------------------------------
__global__ __launch_bounds__(256) void attn_mh_kernel(
    const float* __restrict__ q, const float* __restrict__ k,
    const float* __restrict__ v, const float* __restrict__ scale_p,
    float* __restrict__ msgs)
{
  const int bid = blockIdx.x;
  const int h = bid & 7, qc = bid >> 3;       // qc 0..31
  const int q0 = qc * 16;
  const int tid = threadIdx.x;
  __shared__ __align__(16) float Kh[512 * 32];
  __shared__ __align__(16) float Vh[512 * 32];
  __shared__ unsigned short pb[16 * 512];

  for (int idx = tid; idx < 4096; idx += 256) {
    int j = idx >> 3, part = idx & 7;
    int chs = part ^ (j & 7);
    *(f32x4*)&Kh[j * 32 + chs * 4] =
        *(const f32x4*)&k[(size_t)j * 256 + h * 32 + part * 4];
    *(f32x4*)&Vh[j * 32 + chs * 4] =
        *(const f32x4*)&v[(size_t)j * 256 + h * 32 + part * 4];
  }
  const int qi = tid >> 4, l = tid & 15;
  f32x4 qr[8];
#pragma unroll
  for (int p = 0; p < 8; ++p)
    qr[p] = *(const f32x4*)&q[(size_t)(q0 + qi) * 256 + h * 32 + p * 4];
  const float scale = scale_p[0];
  __syncthreads();

  float pj[32];
  float mx = -1e30f;
#pragma unroll
  for (int jj = 0; jj < 32; ++jj) {
    int j = jj * 16 + l;
    const float* kr = &Kh[j * 32];
    int sw = j & 7;
    float s = 0.f;
#pragma unroll
    for (int p = 0; p < 8; ++p) {
      f32x4 kv = *(const f32x4*)&kr[(p ^ sw) * 4];
      s += kv.x * qr[p].x + kv.y * qr[p].y + kv.z * qr[p].z + kv.w * qr[p].w;
    }
    s *= scale;
    pj[jj] = s;
    mx = fmaxf(mx, s);
  }
#pragma unroll
  for (int o = 1; o < 16; o <<= 1) mx = fmaxf(mx, __shfl_xor(mx, o, 16));
  float sum = 0.f;
#pragma unroll
  for (int jj = 0; jj < 32; ++jj) {
    float e = __expf(pj[jj] - mx);
    pj[jj] = e;
    sum += e;
  }
#pragma unroll
  for (int o = 1; o < 16; o <<= 1) sum += __shfl_xor(sum, o, 16);
  float inv = 1.f / sum;
#pragma unroll
  for (int jj = 0; jj < 32; ++jj)
    pb[qi * 512 + jj * 16 + l] = f2bf(pj[jj] * inv);
  __syncthreads();

  // PV: thread (qi, d-pair l): d0 = 2l
  float m0 = 0.f, m1 = 0.f;
  const unsigned short* pq = &pb[qi * 512];
  for (int j = 0; j < 512; ++j) {
    float p = bf2f(pq[j]);
    int chs = (l >> 1) ^ (j & 7);
    const float* vr = &Vh[j * 32 + chs * 4 + ((2 * l) & 3)];
    m0 += p * vr[0];
    m1 += p * vr[1];
  }
  float* mo = &msgs[(size_t)(q0 + qi) * 256 + h * 32 + 2 * l];
  mo[0] = m0;
  mo[1] = m1;
}

// ---------------------------------------------------------------------------
// Out-proj + residual + LayerNorm. Block per 8 nodes (amortizes wo reads).
// ---------------------------------------------------------------------------
__global__ __launch_bounds__(256) void outln_kernel(
    const float* __restrict__ msgs, const float* __restrict__ nodes,
    const float* __restrict__ woT, const float* __restrict__ bo,
    const float* __restrict__ lng, const float* __restrict__ lnb,
    float* __restrict__ enh)
{
  const int blk = blockIdx.x;
  const int co = threadIdx.x;
  __shared__ float ms[8][256];
  __shared__ float red1[8][4], red2[8][4];
  for (int i = co; i < 2048; i += 256)
    ms[i >> 8][i & 255] = msgs[blk * 2048 + i];
  __syncthreads();
  float yv[8];
  float bo_ = bo[co];
#pragma unroll
  for (int r = 0; r < 8; ++r)
    yv[r] = nodes[(size_t)(blk * 8 + r) * 256 + co] + bo_;
  for (int ci = 0; ci < 256; ++ci) {
    float w = woT[ci * 256 + co];
#pragma unroll
    for (int r = 0; r < 8; ++r) yv[r] += ms[r][ci] * w;
  }
  const int wv = co >> 6, lane = co & 63;
#pragma unroll
  for (int r = 0; r < 8; ++r) {
    float s1 = yv[r], s2 = yv[r] * yv[r];
#pragma unroll
    for (int o = 1; o < 64; o <<= 1) {
      s1 += __shfl_xor(s1, o);
      s2 += __shfl_xor(s2, o);
    }
    if (lane == 0) { red1[r][wv] = s1; red2[r][wv] = s2; }
  }
  __syncthreads();
  float lg = lng[co], lb = lnb[co];
#pragma unroll
  for (int r = 0; r < 8; ++r) {
    float S1 = red1[r][0] + red1[r][1] + red1[r][2] + red1[r][3];
    float S2 = red2[r][0] + red2[r][1] + red2[r][2] + red2[r][3];
    float mu = S1 * (1.f / 256.f);
    float var = S2 * (1.f / 256.f) - mu * mu;
    enh[(size_t)(blk * 8 + r) * 256 + co] =
        (yv[r] - mu) * rsqrtf(var + EPSV) * lg + lb;
  }
}

// ---------------------------------------------------------------------------
// Per-batch pooling + rec 1x1 conv + BN2 -> yfin[b][c]. Block per batch.
// ---------------------------------------------------------------------------
__global__ __launch_bounds__(256) void final_kernel(
    const float* __restrict__ enh, const float* __restrict__ recT,
    const float* __restrict__ recb,
    const float* __restrict__ bn2g, const float* __restrict__ bn2b,
    const float* __restrict__ bn2m, const float* __restrict__ bn2v,
    float* __restrict__ yfin)
{
  const int b = blockIdx.x;
  const int tid = threadIdx.x;
  const int wv = tid >> 6, l = tid & 63;
  __shared__ float rm[32], wts[32], wgt[256];
  for (int kk = wv; kk < 32; kk += 4) {
    const float* er = enh + (size_t)(b * 32 + kk) * 256;
    float s = er[l] + er[l + 64] + er[l + 128] + er[l + 192];
#pragma unroll
    for (int o = 1; o < 64; o <<= 1) s += __shfl_xor(s, o);
    if (l == 0) rm[kk] = s * (1.f / 256.f);
  }
  __syncthreads();
  if (tid < 32) {
    float m = rm[tid];
    float mx = m;
#pragma unroll
    for (int o = 1; o < 32; o <<= 1) mx = fmaxf(mx, __shfl_xor(mx, o, 32));
    float e = __expf(m - mx);
    float sm = e;
#pragma unroll
    for (int o = 1; o < 32; o <<= 1) sm += __shfl_xor(sm, o, 32);
    wts[tid] = e / sm;
  }
  __syncthreads();
  float wsum = 0.f;
  for (int kk = 0; kk < 32; ++kk)
    wsum += enh[(size_t)(b * 32 + kk) * 256 + tid] * wts[kk];
  wgt[tid] = wsum;
  __syncthreads();
  const int co = tid;
  float yv = recb[co];
  for (int ci = 0; ci < 256; ++ci)
    yv += wgt[ci] * recT[ci * 256 + co];
  float s = bn2g[co] / sqrtf(bn2v[co] + EPSV);
  yfin[b * 256 + co] = yv * s + (bn2b[co] - bn2m[co] * s);
}

// ---------------------------------------------------------------------------
// out = x + yfin[b][c] broadcast. Block per (b,c) plane (6400 f32 = 1600 f4).
// ---------------------------------------------------------------------------
__global__ __launch_bounds__(256) void add_kernel(
    const float* __restrict__ x, const float* __restrict__ yfin,
    float* __restrict__ out)
{
  const int bc = blockIdx.x;
  const float a = yfin[bc];
  const f32x4* xp = (const f32x4*)(x + (size_t)bc * 6400);
  f32x4* op = (f32x4*)(out + (size_t)bc * 6400);
  for (int i = threadIdx.x; i < 1600; i += 256) {
    f32x4 v = xp[i];
    v.x += a; v.y += a; v.z += a; v.w += a;
    op[i] = v;
  }
}

extern "C" void kernel_launch(void* const* d_in, const int* in_sizes, int n_in,
                              void* d_out, int out_size, void* d_ws, size_t ws_size,
                              hipStream_t stream)
{
  const float* x      = (const float*)d_in[0];
  const float* boxes  = (const float*)d_in[1];
  const float* conv_w = (const float*)d_in[2];
  const float* conv_b = (const float*)d_in[3];
  const float* bn1g   = (const float*)d_in[4];
  const float* bn1b   = (const float*)d_in[5];
  const float* bn1m   = (const float*)d_in[6];
  const float* bn1v   = (const float*)d_in[7];
  const float* wq     = (const float*)d_in[8];
  const float* bq     = (const float*)d_in[9];
  const float* wk     = (const float*)d_in[10];
  const float* bkp    = (const float*)d_in[11];
  const float* wv     = (const float*)d_in[12];
  const float* bv     = (const float*)d_in[13];
  const float* scale  = (const float*)d_in[14];
  const float* wo     = (const float*)d_in[15];
  const float* bo     = (const float*)d_in[16];
  const float* lng    = (const float*)d_in[17];
  const float* lnb    = (const float*)d_in[18];
  const float* rec_w  = (const float*)d_in[19];
  const float* rec_b  = (const float*)d_in[20];
  const float* bn2g   = (const float*)d_in[21];
  const float* bn2b   = (const float*)d_in[22];
  const float* bn2m   = (const float*)d_in[23];
  const float* bn2v   = (const float*)d_in[24];
  float* out = (float*)d_out;

  char* ws = (char*)d_ws;
  unsigned short* Wr = (unsigned short*)(ws);                // 1,179,648 B
  float* wT    = (float*)(ws + 2097152);                     // 1,310,720 B
  float* nodes = (float*)(ws + 4194304);
  float* qb    = nodes + 131072;
  float* kb    = qb + 131072;
  float* vb    = kb + 131072;
  float* enh   = vb + 131072;
  float* yfin  = enh + 131072;                               // 16 KB
  float* msgs  = yfin + 4096;                                // 512 KB
  // xin (NHWC bf16, 52.4 MB) + 1KB zero pad in d_ws. zpad directly follows
  // xin so roiconv's OOB offset (52428800) lands in it. Re-zeroed every call.
  unsigned short* xin = (unsigned short*)(ws + 8388608);
  float* zpad = (float*)(ws + 8388608 + 52428800);

  hipLaunchKernelGGL(prep_fused_kernel, dim3(4864), dim3(256), 0, stream,
                     x, xin, conv_w, Wr, zpad, wq, wk, wv, wo, rec_w, wT);
  hipLaunchKernelGGL(roiconv_kernel, dim3(256), dim3(512), 0, stream,
                     xin, boxes, conv_b, bn1g, bn1b, bn1m, bn1v, Wr, nodes);
  hipLaunchKernelGGL(qkv_kernel, dim3(128), dim3(256), 0, stream,
                     nodes, wT, bq, bkp, bv, qb, kb, vb);
  hipLaunchKernelGGL(attn_mh_kernel, dim3(256), dim3(256), 0, stream,
                     qb, kb, vb, scale, msgs);
  hipLaunchKernelGGL(outln_kernel, dim3(64), dim3(256), 0, stream,
                     msgs, nodes, wT + 3 * 65536, bo, lng, lnb, enh);
  hipLaunchKernelGGL(final_kernel, dim3(16), dim3(256), 0, stream,
                     enh, wT + 4 * 65536, rec_b, bn2g, bn2b, bn2m, bn2v, yfin);
  hipLaunchKernelGGL(add_kernel, dim3(4096), dim3(256), 0, stream, x, yfin, out);
}